// Round 1
// baseline (1030.267 us; speedup 1.0000x reference)
//
#include <hip/hip_runtime.h>

#define N_NODES 50000
#define N_EDGES 1600000
#define BATCH   4
#define T_STEPS 50
#define DT      0.02f
#define G       8   // lanes per node group in step kernel

// ---------------- setup kernels ----------------

__global__ __launch_bounds__(256) void init_kernel(
    const float* __restrict__ bias, const float* __restrict__ time_const,
    float* __restrict__ alpha, float4* __restrict__ v4,
    float4* __restrict__ rates0, int* __restrict__ count)
{
    int n = blockIdx.x * 256 + threadIdx.x;
    if (n >= N_NODES) return;
    float tau = fmaxf(time_const[n], DT);
    alpha[n] = DT / tau;
    float b = bias[n];
    v4[n] = make_float4(b, b, b, b);
    float r = fmaxf(b, 0.0f);
    rates0[n] = make_float4(r, r, r, r);
    count[n] = 0;
}

__global__ __launch_bounds__(256) void count_kernel(
    const int* __restrict__ tgt, int* __restrict__ count)
{
    int e = blockIdx.x * 256 + threadIdx.x;
    if (e >= N_EDGES) return;
    atomicAdd(&count[tgt[e]], 1);
}

// single-block exclusive scan over 50000 counts
__global__ __launch_bounds__(1024) void scan_kernel(
    const int* __restrict__ count, int* __restrict__ offsets, int* __restrict__ cursor)
{
    __shared__ int partial[1024];
    int tid = threadIdx.x;
    const int chunk = (N_NODES + 1023) / 1024;   // 49
    int begin = tid * chunk;
    int end = min(begin + chunk, N_NODES);
    int s = 0;
    for (int i = begin; i < end; ++i) s += count[i];
    partial[tid] = s;
    __syncthreads();
    for (int off = 1; off < 1024; off <<= 1) {
        int v = (tid >= off) ? partial[tid - off] : 0;
        __syncthreads();
        partial[tid] += v;
        __syncthreads();
    }
    int running = (tid == 0) ? 0 : partial[tid - 1];
    for (int i = begin; i < end; ++i) {
        offsets[i] = running;
        cursor[i]  = running;
        running += count[i];
    }
    if (tid == 1023) offsets[N_NODES] = partial[1023];
}

__global__ __launch_bounds__(256) void fill_kernel(
    const int* __restrict__ src, const int* __restrict__ tgt,
    const float* __restrict__ sign, const float* __restrict__ syn_count,
    const float* __restrict__ syn_strength,
    int* __restrict__ cursor, int2* __restrict__ edges)
{
    int e = blockIdx.x * 256 + threadIdx.x;
    if (e >= N_EDGES) return;
    float w = sign[e] * fmaxf(syn_count[e], 0.0f) * fmaxf(syn_strength[e], 0.0f);
    int pos = atomicAdd(&cursor[tgt[e]], 1);
    edges[pos] = make_int2(src[e], __float_as_int(w));
}

// ---------------- per-step fused gather + Euler update ----------------
// one G-lane group per target node; batch (4) folded into float4

__global__ __launch_bounds__(256) void step_kernel(
    const float4* __restrict__ rates_in, float4* __restrict__ rates_out,
    float4* __restrict__ v4,
    const float* __restrict__ alpha, const float* __restrict__ bias,
    const int* __restrict__ offsets, const int2* __restrict__ edges,
    const float* __restrict__ x, float* __restrict__ out, int t)
{
    int node = blockIdx.x * (256 / G) + (threadIdx.x / G);
    int lane = threadIdx.x & (G - 1);
    if (node >= N_NODES) return;

    int beg = offsets[node], end = offsets[node + 1];
    float4 acc = make_float4(0.f, 0.f, 0.f, 0.f);
    for (int i = beg + lane; i < end; i += G) {
        int2 er = edges[i];
        float w = __int_as_float(er.y);
        float4 r = rates_in[er.x];
        acc.x = fmaf(r.x, w, acc.x);
        acc.y = fmaf(r.y, w, acc.y);
        acc.z = fmaf(r.z, w, acc.z);
        acc.w = fmaf(r.w, w, acc.w);
    }
#pragma unroll
    for (int m = 1; m < G; m <<= 1) {
        acc.x += __shfl_xor(acc.x, m, 64);
        acc.y += __shfl_xor(acc.y, m, 64);
        acc.z += __shfl_xor(acc.z, m, 64);
        acc.w += __shfl_xor(acc.w, m, 64);
    }
    if (lane == 0) {
        float a = alpha[node];
        float b = bias[node];
        float4 vv = v4[node];
        const int TN = T_STEPS * N_NODES;
        int base = t * N_NODES + node;
        float4 vn;
        vn.x = vv.x + a * (b + acc.x + x[base         ] - vv.x);
        vn.y = vv.y + a * (b + acc.y + x[base +     TN] - vv.y);
        vn.z = vv.z + a * (b + acc.z + x[base + 2 * TN] - vv.z);
        vn.w = vv.w + a * (b + acc.w + x[base + 3 * TN] - vv.w);
        v4[node] = vn;
        float4 r = make_float4(fmaxf(vn.x, 0.f), fmaxf(vn.y, 0.f),
                               fmaxf(vn.z, 0.f), fmaxf(vn.w, 0.f));
        rates_out[node] = r;
        out[base         ] = r.x;
        out[base +     TN] = r.y;
        out[base + 2 * TN] = r.z;
        out[base + 3 * TN] = r.w;
    }
}

// ---------------- launch ----------------

extern "C" void kernel_launch(void* const* d_in, const int* in_sizes, int n_in,
                              void* d_out, int out_size, void* d_ws, size_t ws_size,
                              hipStream_t stream) {
    const float* x            = (const float*)d_in[0];
    const float* bias         = (const float*)d_in[1];
    const float* time_const   = (const float*)d_in[2];
    const float* sign         = (const float*)d_in[3];
    const float* syn_count    = (const float*)d_in[4];
    const float* syn_strength = (const float*)d_in[5];
    const int*   src_idx      = (const int*)d_in[6];
    const int*   tgt_idx      = (const int*)d_in[7];
    float* out = (float*)d_out;

    char* ws = (char*)d_ws;
    size_t off = 0;
    auto alloc = [&](size_t bytes) -> void* {
        void* p = ws + off;
        off = (off + bytes + 255) & ~(size_t)255;
        return p;
    };
    float4* v4      = (float4*)alloc((size_t)N_NODES * 16);
    float4* rates_a = (float4*)alloc((size_t)N_NODES * 16);
    float4* rates_b = (float4*)alloc((size_t)N_NODES * 16);
    float*  alpha   = (float*) alloc((size_t)N_NODES * 4);
    int*    offsets = (int*)   alloc((size_t)(N_NODES + 1) * 4);
    int*    cursor  = (int*)   alloc((size_t)N_NODES * 4);
    int*    count   = (int*)   alloc((size_t)N_NODES * 4);
    int2*   edges   = (int2*)  alloc((size_t)N_EDGES * 8);

    int nb_nodes = (N_NODES + 255) / 256;
    int nb_edges = (N_EDGES + 255) / 256;

    init_kernel<<<nb_nodes, 256, 0, stream>>>(bias, time_const, alpha, v4, rates_a, count);
    count_kernel<<<nb_edges, 256, 0, stream>>>(tgt_idx, count);
    scan_kernel<<<1, 1024, 0, stream>>>(count, offsets, cursor);
    fill_kernel<<<nb_edges, 256, 0, stream>>>(src_idx, tgt_idx, sign, syn_count,
                                              syn_strength, cursor, edges);

    int nb_step = (N_NODES * G + 255) / 256;
    for (int t = 0; t < T_STEPS; ++t) {
        const float4* rin  = (t & 1) ? rates_b : rates_a;
        float4*       rout = (t & 1) ? rates_a : rates_b;
        step_kernel<<<nb_step, 256, 0, stream>>>(rin, rout, v4, alpha, bias,
                                                 offsets, edges, x, out, t);
    }
}

// Round 2
// 978.599 us; speedup vs baseline: 1.0528x; 1.0528x over previous
//
#include <hip/hip_runtime.h>
#include <hip/hip_fp16.h>

#define N_NODES 50000
#define N_EDGES 1600000
#define BATCH   4
#define T_STEPS 50
#define DT      0.02f
#define G       8   // lanes per node group in step kernel

// ---------------- setup kernels ----------------

__global__ __launch_bounds__(256) void init_kernel(
    const float* __restrict__ bias, const float* __restrict__ time_const,
    float* __restrict__ alpha, float* __restrict__ v /* [4][N] SoA */,
    float4* __restrict__ rates0, int* __restrict__ count)
{
    int n = blockIdx.x * 256 + threadIdx.x;
    if (n >= N_NODES) return;
    float tau = fmaxf(time_const[n], DT);
    alpha[n] = DT / tau;
    float b = bias[n];
    v[n] = b; v[N_NODES + n] = b; v[2 * N_NODES + n] = b; v[3 * N_NODES + n] = b;
    float r = fmaxf(b, 0.0f);
    rates0[n] = make_float4(r, r, r, r);
    count[n] = 0;
}

__global__ __launch_bounds__(256) void count_kernel(
    const int* __restrict__ tgt, int* __restrict__ count)
{
    int e = blockIdx.x * 256 + threadIdx.x;
    if (e >= N_EDGES) return;
    atomicAdd(&count[tgt[e]], 1);
}

// single-block exclusive scan over 50000 counts
__global__ __launch_bounds__(1024) void scan_kernel(
    const int* __restrict__ count, int* __restrict__ offsets, int* __restrict__ cursor)
{
    __shared__ int partial[1024];
    int tid = threadIdx.x;
    const int chunk = (N_NODES + 1023) / 1024;   // 49
    int begin = tid * chunk;
    int end = min(begin + chunk, N_NODES);
    int s = 0;
    for (int i = begin; i < end; ++i) s += count[i];
    partial[tid] = s;
    __syncthreads();
    for (int off = 1; off < 1024; off <<= 1) {
        int v = (tid >= off) ? partial[tid - off] : 0;
        __syncthreads();
        partial[tid] += v;
        __syncthreads();
    }
    int running = (tid == 0) ? 0 : partial[tid - 1];
    for (int i = begin; i < end; ++i) {
        offsets[i] = running;
        cursor[i]  = running;
        running += count[i];
    }
    if (tid == 1023) offsets[N_NODES] = partial[1023];
}

__global__ __launch_bounds__(256) void fill_kernel(
    const int* __restrict__ src, const int* __restrict__ tgt,
    const float* __restrict__ sign, const float* __restrict__ syn_count,
    const float* __restrict__ syn_strength,
    int* __restrict__ cursor, unsigned int* __restrict__ edges)
{
    int e = blockIdx.x * 256 + threadIdx.x;
    if (e >= N_EDGES) return;
    float w = sign[e] * fmaxf(syn_count[e], 0.0f) * fmaxf(syn_strength[e], 0.0f);
    unsigned int hw = (unsigned int)__half_as_ushort(__float2half(w));
    unsigned int rec = (unsigned int)src[e] | (hw << 16);
    int pos = atomicAdd(&cursor[tgt[e]], 1);
    edges[pos] = rec;
}

// ---------------- per-step fused gather + Euler update ----------------
// one G-lane group per target node; batch (4) folded into float4 gathers.
// Edge record: low 16 bits = src node, high 16 bits = fp16 weight.

__device__ __forceinline__ float rec_w(unsigned int rec) {
    return __half2float(__ushort_as_half((unsigned short)(rec >> 16)));
}

__global__ __launch_bounds__(256) void step_kernel(
    const float4* __restrict__ rates_in, float* __restrict__ rates_out,
    float* __restrict__ v /* [4][N] SoA */,
    const float* __restrict__ alpha, const float* __restrict__ bias,
    const int* __restrict__ offsets, const unsigned int* __restrict__ edges,
    const float* __restrict__ x, float* __restrict__ out, int t)
{
    int node = blockIdx.x * (256 / G) + (threadIdx.x / G);
    int lane = threadIdx.x & (G - 1);
    if (node >= N_NODES) return;

    int beg = offsets[node], end = offsets[node + 1];
    float4 acc = make_float4(0.f, 0.f, 0.f, 0.f);

    // software-pipelined, unroll-2; sanitized zero records are no-ops (w=0)
    int i = beg + lane;
    unsigned int r0 = (i < end)     ? edges[i]     : 0u;
    unsigned int r1 = (i + G < end) ? edges[i + G] : 0u;
    while (i < end) {
        unsigned int n0 = (i + 2 * G < end) ? edges[i + 2 * G] : 0u;
        unsigned int n1 = (i + 3 * G < end) ? edges[i + 3 * G] : 0u;
        float4 a0 = rates_in[r0 & 0xFFFFu];
        float4 a1 = rates_in[r1 & 0xFFFFu];
        float w0 = rec_w(r0);
        float w1 = rec_w(r1);
        acc.x = fmaf(a0.x, w0, acc.x);
        acc.y = fmaf(a0.y, w0, acc.y);
        acc.z = fmaf(a0.z, w0, acc.z);
        acc.w = fmaf(a0.w, w0, acc.w);
        acc.x = fmaf(a1.x, w1, acc.x);
        acc.y = fmaf(a1.y, w1, acc.y);
        acc.z = fmaf(a1.z, w1, acc.z);
        acc.w = fmaf(a1.w, w1, acc.w);
        r0 = n0; r1 = n1;
        i += 2 * G;
    }

#pragma unroll
    for (int m = 1; m < G; m <<= 1) {
        acc.x += __shfl_xor(acc.x, m, 64);
        acc.y += __shfl_xor(acc.y, m, 64);
        acc.z += __shfl_xor(acc.z, m, 64);
        acc.w += __shfl_xor(acc.w, m, 64);
    }

    if (lane < 4) {   // lane l handles batch element l
        float sum = (lane == 0) ? acc.x : (lane == 1) ? acc.y
                  : (lane == 2) ? acc.z : acc.w;
        float a = alpha[node];
        float b = bias[node];
        const int TN = T_STEPS * N_NODES;
        int vi = lane * N_NODES + node;
        int oi = lane * TN + t * N_NODES + node;
        float vv = v[vi];
        float vn = vv + a * (b + sum + x[oi] - vv);
        v[vi] = vn;
        float r = fmaxf(vn, 0.f);
        rates_out[node * 4 + lane] = r;
        out[oi] = r;
    }
}

// ---------------- launch ----------------

extern "C" void kernel_launch(void* const* d_in, const int* in_sizes, int n_in,
                              void* d_out, int out_size, void* d_ws, size_t ws_size,
                              hipStream_t stream) {
    const float* x            = (const float*)d_in[0];
    const float* bias         = (const float*)d_in[1];
    const float* time_const   = (const float*)d_in[2];
    const float* sign         = (const float*)d_in[3];
    const float* syn_count    = (const float*)d_in[4];
    const float* syn_strength = (const float*)d_in[5];
    const int*   src_idx      = (const int*)d_in[6];
    const int*   tgt_idx      = (const int*)d_in[7];
    float* out = (float*)d_out;

    char* ws = (char*)d_ws;
    size_t off = 0;
    auto alloc = [&](size_t bytes) -> void* {
        void* p = ws + off;
        off = (off + bytes + 255) & ~(size_t)255;
        return p;
    };
    float* v        = (float*)alloc((size_t)N_NODES * 4 * 4);   // [4][N] SoA
    float* rates_a  = (float*)alloc((size_t)N_NODES * 16);      // float4 per node
    float* rates_b  = (float*)alloc((size_t)N_NODES * 16);
    float* alpha    = (float*)alloc((size_t)N_NODES * 4);
    int*   offsets  = (int*)  alloc((size_t)(N_NODES + 1) * 4);
    int*   cursor   = (int*)  alloc((size_t)N_NODES * 4);
    int*   count    = (int*)  alloc((size_t)N_NODES * 4);
    unsigned int* edges = (unsigned int*)alloc((size_t)N_EDGES * 4);

    int nb_nodes = (N_NODES + 255) / 256;
    int nb_edges = (N_EDGES + 255) / 256;

    init_kernel<<<nb_nodes, 256, 0, stream>>>(bias, time_const, alpha, v,
                                              (float4*)rates_a, count);
    count_kernel<<<nb_edges, 256, 0, stream>>>(tgt_idx, count);
    scan_kernel<<<1, 1024, 0, stream>>>(count, offsets, cursor);
    fill_kernel<<<nb_edges, 256, 0, stream>>>(src_idx, tgt_idx, sign, syn_count,
                                              syn_strength, cursor, edges);

    int nb_step = (N_NODES * G + 255) / 256;
    for (int t = 0; t < T_STEPS; ++t) {
        const float4* rin = (const float4*)((t & 1) ? rates_b : rates_a);
        float*        rout = (t & 1) ? rates_a : rates_b;
        step_kernel<<<nb_step, 256, 0, stream>>>(rin, rout, v, alpha, bias,
                                                 offsets, edges, x, out, t);
    }
}